// Round 1
// baseline (837.130 us; speedup 1.0000x reference)
//
#include <hip/hip_runtime.h>

// SnakeBetaAA: y = x + sin^2(x*exp(alpha_c)) / (exp(beta_c) + eps), then
// reflect-pad(6) + 12-tap depthwise FIR (VALID) -> per-row output length T+1.
//
// Layout: grid.x = tiles per row (16), grid.y = rows (B*C = 4096).
// Each block stages snake(x) for TILE outputs + 11 halo into LDS, then
// computes the FIR with strided per-thread outputs so loads AND stores are
// coalesced dword accesses.

#define T_LEN   32768
#define C_LEN   512
#define OUT_T   (T_LEN + 1)        // even kernel, VALID conv on T+2*6 input
#define KSIZE   12
#define PADW    6
#define TILE    2048
#define TPB     256
#define EPS_F   1e-9f

__global__ __launch_bounds__(TPB) void snake_aa_kernel(
    const float* __restrict__ x,
    const float* __restrict__ alpha,
    const float* __restrict__ beta,
    const float* __restrict__ filt,
    float* __restrict__ out,
    int n_tiles)
{
    // staged snake(x) values: up to (TILE+1) outputs in last tile + K-1 halo
    __shared__ float sy[TILE + KSIZE];   // 2060 floats = 8240 B

    const int row  = blockIdx.y;               // row = b*C + c
    const int tile = blockIdx.x;
    const int c    = row & (C_LEN - 1);

    const int s = tile * TILE;                            // first output idx
    const int e = (tile == n_tiles - 1) ? OUT_T : (s + TILE); // one past last
    const int n_y = e - s + (KSIZE - 1);                  // staged count

    // per-channel snake params (uniform across block)
    const float a    = __expf(alpha[c]);
    const float binv = 1.0f / (__expf(beta[c]) + EPS_F);

    // filter taps -> registers (uniform loads; filter is symmetric)
    float f[KSIZE];
#pragma unroll
    for (int k = 0; k < KSIZE; ++k) f[k] = filt[k];

    const float* __restrict__ xrow = x + (size_t)row * T_LEN;

    // Stage snake(x[reflect(j)]) for j in [s-6, e+5].  Coalesced: consecutive
    // threads -> consecutive j except at the (rare) reflected row edges.
    for (int i = threadIdx.x; i < n_y; i += TPB) {
        int j = s - PADW + i;
        j = (j < 0) ? -j : j;                       // reflect left (no edge repeat)
        j = (j >= T_LEN) ? (2 * (T_LEN - 1) - j) : j; // reflect right
        const float v  = xrow[j];
        const float sn = __sinf(v * a);
        sy[i] = v + sn * sn * binv;
    }
    __syncthreads();

    // FIR: out[t] = sum_k sy[t-s+k] * f[k].  Strided per-thread outputs keep
    // each global_store_dword wave-coalesced; LDS reads are lane-consecutive
    // (2 lanes/bank on wave64 -> conflict-free).
    float* __restrict__ orow = out + (size_t)row * OUT_T;
    for (int t = s + (int)threadIdx.x; t < e; t += TPB) {
        const int base = t - s;
        float acc = 0.0f;
#pragma unroll
        for (int k = 0; k < KSIZE; ++k) acc += sy[base + k] * f[k];
        orow[t] = acc;
    }
}

extern "C" void kernel_launch(void* const* d_in, const int* in_sizes, int n_in,
                              void* d_out, int out_size, void* d_ws, size_t ws_size,
                              hipStream_t stream) {
    const float* x     = (const float*)d_in[0];
    const float* alpha = (const float*)d_in[1];
    const float* beta  = (const float*)d_in[2];
    const float* filt  = (const float*)d_in[3];
    float* out = (float*)d_out;

    const int rows    = in_sizes[0] / T_LEN;      // B*C = 4096
    const int n_tiles = T_LEN / TILE;             // 16; last tile takes the +1

    dim3 grid(n_tiles, rows);
    dim3 block(TPB);
    snake_aa_kernel<<<grid, block, 0, stream>>>(x, alpha, beta, filt, out, n_tiles);
}